// Round 6
// baseline (222.615 us; speedup 1.0000x reference)
//
#include <hip/hip_runtime.h>
#include <math.h>

#define B_ 32
#define Q_ 1024
#define G_ 64
#define T_ 256    // threads per batch (4 waves)
#define K4 4      // columns per thread (Q_ / T_)
#define LROWS 32  // cost rows resident in LDS (mean g = 31.5)

// ---- cross-lane helpers -------------------------------------------------
// row_ror:N DPP rotates within each 16-lane row; all source lanes valid.
template<int CTRL>
__device__ __forceinline__ int dpp_i32(int x) {
    return __builtin_amdgcn_update_dpp(x, x, CTRL, 0xF, 0xF, false);
}
template<int CTRL>
__device__ __forceinline__ double dpp_f64(double x) {
    union { double d; int i[2]; } a; a.d = x;
    union { int i[2]; double d; } r;
    r.i[0] = __builtin_amdgcn_update_dpp(a.i[0], a.i[0], CTRL, 0xF, 0xF, false);
    r.i[1] = __builtin_amdgcn_update_dpp(a.i[1], a.i[1], CTRL, 0xF, 0xF, false);
    return r.d;
}
#define ROR1 0x121
#define ROR2 0x122
#define ROR4 0x124
#define ROR8 0x128

__device__ __forceinline__ double readlane_f64(double x, int sl) {
    const int s = __builtin_amdgcn_readfirstlane(sl);
    union { double d; int i2[2]; } a; a.d = x;
    union { int i2[2]; double d; } r;
    r.i2[0] = __builtin_amdgcn_readlane(a.i2[0], s);
    r.i2[1] = __builtin_amdgcn_readlane(a.i2[1], s);
    return r.d;
}
__device__ __forceinline__ int readlane_i32(int x, int sl) {
    return __builtin_amdgcn_readlane(x, __builtin_amdgcn_readfirstlane(sl));
}

// Fused: per-block cost build (LDS rows 0..31, global ctg rows 32..63, same-XCD
// L2) + 4-wave register-resident Jonker-Volgenant.
// Thread t owns columns j = t + 256k (k<4): v, shortest, SC-bits, costs in regs.
// u / col4row / asg are lane-keyed replicas identical in every wave.
// LDS on step path: ONLY the 4-slot parity-buffered (val,idx) combine + 1 barrier.
template<bool HASWS>
__global__ __launch_bounds__(256) void matcher_fused(
    const float* __restrict__ obj, const float* __restrict__ cd,
    const float* __restrict__ gi, const int* __restrict__ ngt,
    float* __restrict__ ctg, float* __restrict__ out_ind,
    float* __restrict__ out_mask)
{
    __shared__ float  ldsct[LROWS * 1025];     // 131200 B, stride 1025: conflict-free
    __shared__ int    row4col_[Q_];
    __shared__ int    path_[Q_];
    __shared__ __align__(16) char scratch_[64 * 65 * 4];  // tile (build) / sh dump (match)
    __shared__ double comb_v[2][4];
    __shared__ int    comb_j[2][4];

    float (*tile)[65] = (float (*)[65])scratch_;
    double* sh_lds    = (double*)scratch_;

    const int b = blockIdx.x;
    const int t = threadIdx.x;
    const int l = t & 63;
    const int w = t >> 6;
    const int g = ngt[b];

    const float* objb = obj + (b << 10);
    const float* cdb  = cd + ((size_t)b << 16);
    const float* gib  = gi + ((size_t)b << 16);

    for (int j = t; j < Q_; j += T_) row4col_[j] = -1;

    // ---- build phase: cost rows into LDS (i<32) / same-XCD global (i>=32) ----
    if (g > 0) {
        const float4* cd4 = (const float4*)cdb;
        const float4* gi4 = (const float4*)gib;
        for (int jb = 0; jb < Q_; jb += 64) {
            #pragma unroll
            for (int p = 0; p < 4; ++p) {
                const int f  = t + (p << 8);
                const int jj = f >> 4;            // 0..63
                const int i0 = (f & 15) << 2;     // 0,4,..,60
                const int j  = jb + jj;
                const float om = __fmul_rn(5.0f, -objb[j]);
                const float4 c4 = cd4[(j << 4) + (i0 >> 2)];
                const float4 q4 = gi4[(j << 4) + (i0 >> 2)];
                tile[i0 + 0][jj] = __fadd_rn(__fadd_rn(om, __fmul_rn(10.0f, c4.x)), __fmul_rn(2.0f, -q4.x));
                tile[i0 + 1][jj] = __fadd_rn(__fadd_rn(om, __fmul_rn(10.0f, c4.y)), __fmul_rn(2.0f, -q4.y));
                tile[i0 + 2][jj] = __fadd_rn(__fadd_rn(om, __fmul_rn(10.0f, c4.z)), __fmul_rn(2.0f, -q4.z));
                tile[i0 + 3][jj] = __fadd_rn(__fadd_rn(om, __fmul_rn(10.0f, c4.w)), __fmul_rn(2.0f, -q4.w));
            }
            __syncthreads();
            #pragma unroll
            for (int r = 0; r < 16; ++r) {
                const int idx = (r << 8) + t;
                const int i = idx >> 6, jj = idx & 63;   // i fixed per wave: conflict-free
                if (i < g) {
                    const float cv = tile[i][jj];
                    if (i < LROWS) ldsct[i * 1025 + jb + jj] = cv;
                    else if (HASWS) ctg[(((b << 5) + (i - LROWS)) << 10) + jb + jj] = cv;
                }
            }
            __syncthreads();
        }
    } else {
        __syncthreads();
    }

    float objm[K4];
    if (!HASWS) {
        #pragma unroll
        for (int k = 0; k < K4; ++k) objm[k] = __fmul_rn(5.0f, -objb[t + (k << 8)]);
    }
    auto load_row = [&](int i, float* c) {
        if (i < LROWS) {
            #pragma unroll
            for (int k = 0; k < K4; ++k) c[k] = ldsct[i * 1025 + t + (k << 8)];
        } else if (HASWS) {
            #pragma unroll
            for (int k = 0; k < K4; ++k)
                c[k] = ctg[(((b << 5) + (i - LROWS)) << 10) + t + (k << 8)];
        } else {
            #pragma unroll
            for (int k = 0; k < K4; ++k) {
                const int j = t + (k << 8);
                const int idx = (j << 6) + i;
                c[k] = __fadd_rn(__fadd_rn(objm[k], __fmul_rn(10.0f, cdb[idx])),
                                 __fmul_rn(2.0f, -gib[idx]));
            }
        }
    };

    double u_rep   = 0.0;       // u[l], replicated per wave
    int    c4r_rep = -1;        // col4row[l], replicated per wave
    unsigned asg   = 0u;        // bit s: column l + 64s assigned (replicated)
    double v_r[K4];
    #pragma unroll
    for (int k = 0; k < K4; ++k) v_r[k] = 0.0;

    const double INF = __builtin_inf();
    float c_row[K4], c_next[K4];
    unsigned stepctr = 0;

    for (int cur = 0; cur < g; ++cur) {
        if (cur < LROWS) {
            load_row(cur, c_row);              // LDS: cheap, at row start
        } else {
            #pragma unroll
            for (int k = 0; k < K4; ++k) c_row[k] = c_next[k];   // prefetched
        }

        double sh_r[K4];
        #pragma unroll
        for (int k = 0; k < K4; ++k) sh_r[k] = INF;
        unsigned sc = 0u;
        bool inSR = (l == cur);
        int nSR = 0;
        double minv = 0.0;
        int i = cur;
        int sink = -1;
        double ui = readlane_f64(u_rep, i);

        while (sink < 0) {
            ++nSR;
            // ---- scan own 4 columns (exact numpy f64 order) ----
            double cand[K4];
            #pragma unroll
            for (int k = 0; k < K4; ++k) {
                const double r = ((minv + (double)c_row[k]) - ui) - v_r[k];
                const bool notSC = !((sc >> k) & 1u);
                const bool upd = notSC && (r < sh_r[k]);   // strict <
                sh_r[k] = upd ? r : sh_r[k];
                if (upd) path_[t + (k << 8)] = i;          // off critical path
                cand[k] = notSC ? sh_r[k] : INF;
            }
            // ---- in-thread lex min (ties -> smaller k = smaller j) ----
            double bv0 = cand[0]; int bj0 = t;
            if (cand[1] < bv0) { bv0 = cand[1]; bj0 = t + 256; }
            double bv1 = cand[2]; int bj1 = t + 512;
            if (cand[3] < bv1) { bv1 = cand[3]; bj1 = t + 768; }
            double bv = bv0; int bj = bj0;
            if (bv1 < bv0) { bv = bv1; bj = bj1; }
            // ---- in-wave lex min: 4 DPP rors, then merge the 4 row-mins ----
            #pragma unroll
            for (int rr = 0; rr < 4; ++rr) {
                double ov; int oj;
                if (rr == 0)      { ov = dpp_f64<ROR1>(bv); oj = dpp_i32<ROR1>(bj); }
                else if (rr == 1) { ov = dpp_f64<ROR2>(bv); oj = dpp_i32<ROR2>(bj); }
                else if (rr == 2) { ov = dpp_f64<ROR4>(bv); oj = dpp_i32<ROR4>(bj); }
                else              { ov = dpp_f64<ROR8>(bv); oj = dpp_i32<ROR8>(bj); }
                const bool take = (ov < bv) || (ov == bv && oj < bj);
                bv = take ? ov : bv;
                bj = take ? oj : bj;
            }
            double wv = readlane_f64(bv, 0);
            int    wj = readlane_i32(bj, 0);
            #pragma unroll
            for (int gg = 1; gg < 4; ++gg) {
                const double ov = readlane_f64(bv, gg << 4);
                const int    oj = readlane_i32(bj, gg << 4);
                const bool take = (ov < wv) || (ov == wv && oj < wj);
                wv = take ? ov : wv;
                wj = take ? oj : wj;
            }
            // ---- cross-wave combine: parity-buffered slots, ONE barrier/step ----
            const int par = stepctr & 1; ++stepctr;
            if (l == 0) { comb_v[par][w] = wv; comb_j[par][w] = wj; }
            __syncthreads();
            double mv = comb_v[par][0]; int mj = comb_j[par][0];
            #pragma unroll
            for (int w2 = 1; w2 < 4; ++w2) {
                const double ov = comb_v[par][w2];
                const int    oj = comb_j[par][w2];
                const bool take = (ov < mv) || (ov == mv && oj < mj);
                mv = take ? ov : mv;
                mj = take ? oj : mj;
            }
            minv = mv;
            const int jm = mj;
            if (t == (jm & 255)) sc |= (1u << (jm >> 8));
            const int owner = jm & 63, slot = jm >> 6;
            const unsigned ownerAsg = (unsigned)readlane_i32((int)asg, owner);
            if (!((ownerAsg >> slot) & 1u)) {
                sink = jm;
            } else {
                i = row4col_[jm];              // rare: multi-step only
                if (l == i) inSR = true;
                ui = readlane_f64(u_rep, i);
                load_row(i, c_row);            // LDS (i<32) or same-XCD L2
            }
        }

        // ---- dual updates (reference order: u, then v, then augment) ----
        if (l == cur) u_rep += minv;
        if (nSR > 1) {
            #pragma unroll
            for (int k = 0; k < K4; ++k) sh_lds[t + (k << 8)] = sh_r[k];
            __syncthreads();
            if (inSR && l != cur) u_rep += minv - sh_lds[c4r_rep];
        }
        #pragma unroll
        for (int k = 0; k < K4; ++k) {
            const double nv = v_r[k] - (minv - sh_r[k]);
            v_r[k] = ((sc >> k) & 1u) ? nv : v_r[k];
        }

        // prefetch next row if it's a global row: issued AFTER all step barriers,
        // drained at the row-end barrier behind the augment work.
        if (cur + 1 < g && cur + 1 >= LROWS) load_row(cur + 1, c_next);

        // ---- augment: uniform traversal; thread 0 writes LDS; replicas updated ----
        {
            int j = sink;
            while (true) {
                const int ii = path_[j];                     // uniform LDS read
                const int nj = readlane_i32(c4r_rep, ii);    // old col4row[ii]
                if (t == 0) row4col_[j] = ii;
                if (l == ii) c4r_rep = j;
                if (l == (j & 63)) asg |= 1u << (j >> 6);
                j = nj;
                if (ii == cur) break;
            }
        }
        __syncthreads();   // row end: row4col_/path_ visibility + prefetch drain
    }

    for (int j = t; j < Q_; j += T_) {
        const int rc = row4col_[j];
        out_ind [(b << 10) + j] = (rc >= 0) ? (float)rc : 0.0f;
        out_mask[(b << 10) + j] = (rc >= 0) ? 1.0f : 0.0f;
    }
}

extern "C" void kernel_launch(void* const* d_in, const int* in_sizes, int n_in,
                              void* d_out, int out_size, void* d_ws, size_t ws_size,
                              hipStream_t stream)
{
    const float* obj = (const float*)d_in[1];
    const float* cd  = (const float*)d_in[2];
    const float* gi  = (const float*)d_in[3];
    const int*   ngt = (const int*)d_in[4];
    float* out0 = (float*)d_out;
    float* out1 = out0 + B_ * Q_;

    const size_t need = (size_t)B_ * (G_ - LROWS) * Q_ * sizeof(float);  // 4 MB
    if (ws_size >= need) {
        matcher_fused<true><<<B_, T_, 0, stream>>>(obj, cd, gi, ngt,
                                                   (float*)d_ws, out0, out1);
    } else {
        matcher_fused<false><<<B_, T_, 0, stream>>>(obj, cd, gi, ngt,
                                                    nullptr, out0, out1);
    }
}